// Round 3
// baseline (518.641 us; speedup 1.0000x reference)
//
#include <hip/hip_runtime.h>
#include <stdint.h>
#include <stddef.h>

// Problem constants (fixed by the reference)
#define DDIM   512
#define KCL    1024
#define BK     32
#define KSTEPS (DDIM / BK)          // 16
#define RPB    32                   // rows per block (halved: 2 blocks/CU)
#define THR    512                  // threads per block (8 waves)
#define NROWS  65536
#define NBLK   (NROWS / RPB)        // 2048

// A panel in LDS: 32 rows x 512 halves, row padded 512->520 halves (1040 B)
#define SA_STRIDE_H 520
#define SA_ROW_B    (SA_STRIDE_H * 2)           // 1040
#define SA_BYTES    (RPB * SA_ROW_B)            // 33280
#define SMEM_BYTES  (SA_BYTES + 512)            // 33792 -> 2 blocks/CU easily

typedef __attribute__((ext_vector_type(4))) float    floatx4;
typedef __attribute__((ext_vector_type(8))) _Float16 half8;
typedef __attribute__((ext_vector_type(4))) _Float16 half4v;

// ---------------------------------------------------------------------------
// Prep: clusters f32 [1024][512] -> wsB fp16, packed per K-step tile:
//   wsB[ks][c][32]; B consumed via coalesced GLOBAL loads (1 KiB/wave-load).
// also computes c_sq[1024]. One wave per cluster.
// ---------------------------------------------------------------------------
__global__ __launch_bounds__(256) void prep_kernel(const float* __restrict__ clusters,
                                                   _Float16* __restrict__ wsB,
                                                   float* __restrict__ csq) {
    const int l  = threadIdx.x & 63;
    const int c  = (blockIdx.x << 2) + (threadIdx.x >> 6);   // cluster 0..1023
    const int ks = l >> 2;                                   // k-step 0..15
    const int j  = l & 3;                                    // 16B chunk 0..3

    const float* src = clusters + (size_t)c * DDIM + ks * BK + j * 8;
    floatx4 f0 = *(const floatx4*)src;
    floatx4 f1 = *(const floatx4*)(src + 4);

    half8 h;
    h[0] = (_Float16)f0[0]; h[1] = (_Float16)f0[1]; h[2] = (_Float16)f0[2]; h[3] = (_Float16)f0[3];
    h[4] = (_Float16)f1[0]; h[5] = (_Float16)f1[1]; h[6] = (_Float16)f1[2]; h[7] = (_Float16)f1[3];

    *(half8*)(wsB + (size_t)ks * (KCL * BK) + c * BK + j * 8) = h;

    float ss = f0[0]*f0[0] + f0[1]*f0[1] + f0[2]*f0[2] + f0[3]*f0[3]
             + f1[0]*f1[0] + f1[1]*f1[1] + f1[2]*f1[2] + f1[3]*f1[3];
    ss += __shfl_xor(ss, 1,  64);
    ss += __shfl_xor(ss, 2,  64);
    ss += __shfl_xor(ss, 4,  64);
    ss += __shfl_xor(ss, 8,  64);
    ss += __shfl_xor(ss, 16, 64);
    ss += __shfl_xor(ss, 32, 64);
    if (l == 0) csq[c] = ss;
}

// ---------------------------------------------------------------------------
// Main (R3): one block = 32 rows x all 1024 clusters. 8 waves, wave w owns
// cols w*128 as 2(row) x 8(col) tiles of mfma_f32_16x16x32_f16 (acc 64 regs).
//
// R1/R2 lesson: limit is phase serialization with 1 block/CU. This block is
// half-size (512 thr, 33 KiB LDS, ~120 regs -> 4 waves/SIMD) so 2 INDEPENDENT
// blocks co-reside per CU at independent phases: one block's stage/epilogue
// VALU + memory latency hides under the other's MFMA loop. Rows per block
// halve -> B L2 traffic doubles to 2 GiB (~30 us aggregate at L2 BW) — paid
// for by the overlap. K-loop stays barrier-free with B streamed from L2 in a
// register ping-pong at half-K-step granularity (4-col groups).
// ---------------------------------------------------------------------------
__global__ __launch_bounds__(THR, 4)
void cluster_kernel(const float* __restrict__ x,
                    const _Float16* __restrict__ wsB,
                    const float* __restrict__ csq,
                    float* __restrict__ out) {
    extern __shared__ char smem[];
    char*  const sA     = smem;
    float* const xsq    = (float*)(smem + SA_BYTES);        // 32 f32
    float* const rowsum = (float*)(smem + SA_BYTES + 128);  // 32 f32

    const int t      = threadIdx.x;
    const int l      = t & 63;
    const int w      = t >> 6;          // 0..7
    const int lane16 = l & 15;
    const int kgrp   = l >> 4;          // 0..3
    const int row0   = blockIdx.x * RPB;
    const int wcol   = w << 7;          // wave's first column (128-wide slice)

    if (t < 32) { xsq[t] = 0.f; rowsum[t] = 0.f; }
    __syncthreads();

    // ---- stage A panel (32 x 512 f32 -> fp16 LDS), fold in xsq
    {
#pragma unroll
        for (int it = 0; it < 8; ++it) {
            const int g   = it * THR + t;       // float4-chunk index 0..4095
            const int row = g >> 7;             // block-local row (whole wave shares it)
            const int c4  = g & 127;            // float4 chunk within row
            floatx4 f = *(const floatx4*)(x + (size_t)(row0 + row) * DDIM + c4 * 4);
            half4v h;
            h[0] = (_Float16)f[0]; h[1] = (_Float16)f[1];
            h[2] = (_Float16)f[2]; h[3] = (_Float16)f[3];
            *(half4v*)(sA + row * SA_ROW_B + c4 * 8) = h;
            float ss = f[0]*f[0] + f[1]*f[1] + f[2]*f[2] + f[3]*f[3];
            ss += __shfl_xor(ss, 1,  64);
            ss += __shfl_xor(ss, 2,  64);
            ss += __shfl_xor(ss, 4,  64);
            ss += __shfl_xor(ss, 8,  64);
            ss += __shfl_xor(ss, 16, 64);
            ss += __shfl_xor(ss, 32, 64);
            if (l == 0) atomicAdd(&xsq[row], ss);
        }
    }
    __syncthreads();   // the ONLY barrier before the epilogue

    // fragment addresses
    const int abase = lane16 * SA_ROW_B + kgrp * 16;               // + k*64 + rt*16*SA_ROW_B
    const _Float16* const bbase = wsB + (size_t)(wcol + lane16) * BK + kgrp * 8;
    // B frag (ks, ct): bbase + ks*32768 + ct*512 halves; 1 KiB contiguous per wave-load

    floatx4 acc[2][8];
#pragma unroll
    for (int rt = 0; rt < 2; ++rt)
#pragma unroll
        for (int ct = 0; ct < 8; ++ct)
            acc[rt][ct] = (floatx4){0.f, 0.f, 0.f, 0.f};

    // ping-pong at half-step granularity: 32 half-steps, each = 4 col-tiles
    // of one K-step. h -> (ks = h>>1, cg = h&1), cols cg*4..cg*4+3.
    half8 bA[4], bB[4];
#define LOADB(dst, h_)                                                         \
    _Pragma("unroll")                                                          \
    for (int ct = 0; ct < 4; ++ct)                                             \
        dst[ct] = *(const half8*)(bbase + (size_t)((h_) >> 1) * (KCL * BK)     \
                                  + (((h_) & 1) * 4 + ct) * 512);

#define COMPUTE(h_, bsrc)                                                      \
    {                                                                          \
        half8 aF[2];                                                           \
        _Pragma("unroll")                                                      \
        for (int rt = 0; rt < 2; ++rt)                                         \
            aF[rt] = *(const half8*)(sA + abase + ((h_) >> 1) * 64             \
                                     + rt * (16 * SA_ROW_B));                  \
        _Pragma("unroll")                                                      \
        for (int ct = 0; ct < 4; ++ct)                                         \
            _Pragma("unroll")                                                  \
            for (int rt = 0; rt < 2; ++rt)                                     \
                acc[rt][((h_) & 1) * 4 + ct] = __builtin_amdgcn_mfma_f32_16x16x32_f16( \
                    aF[rt], bsrc[ct], acc[rt][((h_) & 1) * 4 + ct], 0, 0, 0);  \
    }

    LOADB(bA, 0);
#pragma unroll
    for (int h = 0; h < 32; h += 2) {
        if (h + 1 < 32) LOADB(bB, h + 1);
        COMPUTE(h, bA);
        if (h + 2 < 32) LOADB(bA, h + 2);
        if (h + 1 < 32) COMPUTE(h + 1, bB);
    }
#undef LOADB
#undef COMPUTE

    // ---- epilogue. C layout: col = lane&15, row = (lane>>4)*4 + reg (m89/m91)
    float cs[8];
#pragma unroll
    for (int ct = 0; ct < 8; ++ct)
        cs[ct] = csq[wcol + ct * 16 + lane16];
    floatx4 xv[2];
#pragma unroll
    for (int rt = 0; rt < 2; ++rt)
        xv[rt] = *(const floatx4*)(xsq + rt * 16 + kgrp * 4);

    float rp[2][4];
#pragma unroll
    for (int rt = 0; rt < 2; ++rt) {
#pragma unroll
        for (int i = 0; i < 4; ++i) {
            const float xr = xv[rt][i];
            float s = 0.f;
#pragma unroll
            for (int ct = 0; ct < 8; ++ct) {
                float d = xr + cs[ct] - 2.0f * acc[rt][ct][i];
                d = fmaxf(d, 0.0f);
                const float q = __builtin_amdgcn_rcpf(1.0f + d);   // ALPHA=1 -> exponent 1
                acc[rt][ct][i] = q;
                s += q;
            }
            rp[rt][i] = s;
        }
    }
    // reduce partial row sums across the 16 lanes sharing kgrp
#pragma unroll
    for (int m = 1; m <= 8; m <<= 1)
#pragma unroll
        for (int rt = 0; rt < 2; ++rt)
#pragma unroll
            for (int i = 0; i < 4; ++i)
                rp[rt][i] += __shfl_xor(rp[rt][i], m, 64);
    if (lane16 == 0) {
#pragma unroll
        for (int rt = 0; rt < 2; ++rt)
#pragma unroll
            for (int i = 0; i < 4; ++i)
                atomicAdd(&rowsum[rt * 16 + kgrp * 4 + i], rp[rt][i]);
    }
    __syncthreads();

    // plain (cached) stores: L2 merges the 64B lane-group quadrants into lines
#pragma unroll
    for (int rt = 0; rt < 2; ++rt) {
        const floatx4 rs = *(const floatx4*)(rowsum + rt * 16 + kgrp * 4);
#pragma unroll
        for (int i = 0; i < 4; ++i) {
            const float inv = __builtin_amdgcn_rcpf(rs[i]);
            float* orow = out + (size_t)(row0 + rt * 16 + kgrp * 4 + i) * KCL + wcol + lane16;
#pragma unroll
            for (int ct = 0; ct < 8; ++ct)
                orow[ct * 16] = acc[rt][ct][i] * inv;
        }
    }
}

extern "C" void kernel_launch(void* const* d_in, const int* in_sizes, int n_in,
                              void* d_out, int out_size, void* d_ws, size_t ws_size,
                              hipStream_t stream) {
    (void)in_sizes; (void)n_in; (void)out_size; (void)ws_size;
    const float* x        = (const float*)d_in[0];
    const float* clusters = (const float*)d_in[1];
    float* out = (float*)d_out;

    _Float16* wsB = (_Float16*)d_ws;                                   // 1 MiB packed fp16 B
    float*    csq = (float*)((char*)d_ws + (size_t)KSTEPS * KCL * BK * 2);  // 4 KiB

    hipFuncSetAttribute((const void*)cluster_kernel,
                        hipFuncAttributeMaxDynamicSharedMemorySize, SMEM_BYTES);

    prep_kernel<<<KCL / 4, 256, 0, stream>>>(clusters, wsB, csq);
    cluster_kernel<<<NBLK, THR, SMEM_BYTES, stream>>>(x, wsB, csq, out);
}

// Round 4
// 479.867 us; speedup vs baseline: 1.0808x; 1.0808x over previous
//
#include <hip/hip_runtime.h>
#include <stdint.h>
#include <stddef.h>

// Problem constants (fixed by the reference)
#define DDIM   512
#define KCL    1024
#define BK     32
#define KSTEPS (DDIM / BK)          // 16
#define RPB    64                   // rows per block
#define THR    1024                 // threads per block (16 waves)
#define NROWS  65536
#define NBLK   (NROWS / RPB)        // 1024

// B ring: 4 slots of one HALF-tile each (512 cols x 32 k fp16 = 32 KiB)
#define HT_HALVES  16384            // halves per half-tile
#define HT_BYTES   32768
#define RING_BYTES (4 * HT_BYTES)   // 131072
#define NHALF      32               // half-tiles total (16 ksteps x 2)
#define WSB_HALVES (NHALF * HT_HALVES)   // 524288 halves = 1 MiB per copy

// A step tile: 64 rows x 32 halves, padded to 40 halves (80 B) per row
#define SA_STRIDE  40
#define SA_ROW_B   (SA_STRIDE * 2)          // 80
#define SA_BYTES   (RPB * SA_ROW_B)         // 5120
#define SMEM_BYTES (RING_BYTES + 2 * SA_BYTES + 512)   // 141824 < 160 KiB

typedef __attribute__((ext_vector_type(4))) float    floatx4;
typedef __attribute__((ext_vector_type(2))) float    floatx2;
typedef __attribute__((ext_vector_type(8))) _Float16 half8;
typedef __attribute__((ext_vector_type(2))) _Float16 half2v;

// async global -> LDS, 16B per lane (global_load_lds_dwordx4)
__device__ __forceinline__ void gload_lds16(const void* g, void* l) {
    __builtin_amdgcn_global_load_lds(
        (const __attribute__((address_space(1))) unsigned char*)g,
        (__attribute__((address_space(3))) unsigned char*)l,
        16, 0, 0);
}

// ---------------------------------------------------------------------------
// Prep: clusters f32 [1024][512] -> wsB fp16 x ncopy replicas.
// Layout per copy: [half-tile hp = ks*2 + (c>>9)] [cloc = c&511] [32 k],
// with the 4 16B chunks of each (cloc, ks) col-row XOR-swizzled:
// chunk j at slot p = (j + (cloc>>1)) & 3 (conflict-free b128 frag reads).
// Replicas spread the B working set across L2 sets (all 256 CUs otherwise
// hammer the same 1 MiB -> same-set contention). Also computes c_sq[1024].
// ---------------------------------------------------------------------------
__global__ __launch_bounds__(256) void prep_kernel(const float* __restrict__ clusters,
                                                   _Float16* __restrict__ wsB,
                                                   float* __restrict__ csq) {
    const int blk  = blockIdx.x & 255;                       // 0..255
    const int copy = blockIdx.x >> 8;                        // replica id
    const int l  = threadIdx.x & 63;
    const int c  = (blk << 2) + (threadIdx.x >> 6);          // cluster 0..1023
    const int ks = l >> 2;                                   // k-step 0..15
    const int j  = l & 3;                                    // 16B chunk 0..3

    const float* src = clusters + (size_t)c * DDIM + ks * BK + j * 8;
    floatx4 f0 = *(const floatx4*)src;
    floatx4 f1 = *(const floatx4*)(src + 4);

    half8 h;
    h[0] = (_Float16)f0[0]; h[1] = (_Float16)f0[1]; h[2] = (_Float16)f0[2]; h[3] = (_Float16)f0[3];
    h[4] = (_Float16)f1[0]; h[5] = (_Float16)f1[1]; h[6] = (_Float16)f1[2]; h[7] = (_Float16)f1[3];

    const int hp   = ks * 2 + (c >> 9);
    const int cloc = c & 511;
    const int p    = (j + (cloc >> 1)) & 3;
    *(half8*)(wsB + (size_t)copy * WSB_HALVES
                  + (size_t)hp * HT_HALVES + cloc * BK + p * 8) = h;

    if (copy == 0) {
        float ss = f0[0]*f0[0] + f0[1]*f0[1] + f0[2]*f0[2] + f0[3]*f0[3]
                 + f1[0]*f1[0] + f1[1]*f1[1] + f1[2]*f1[2] + f1[3]*f1[3];
        ss += __shfl_xor(ss, 1,  64);
        ss += __shfl_xor(ss, 2,  64);
        ss += __shfl_xor(ss, 4,  64);
        ss += __shfl_xor(ss, 8,  64);
        ss += __shfl_xor(ss, 16, 64);
        ss += __shfl_xor(ss, 32, 64);
        if (l == 0) csq[c] = ss;
    }
}

// ---------------------------------------------------------------------------
// Main (R4): one block = 64 rows x all 1024 clusters, 16 waves. Wave w owns
// 32 cols in EACH 512-col half: global cols (h*512 + w*32 + ctl*16 + lane16).
// acc[4 rt][4 ct] (ct = h*2+ctl) = 64 regs.
//
// K-loop = 32 phases (16 ksteps x 2 halves), T3+T4 counted-vmcnt pipeline:
// ring of 4 half-tile slots; phase p reads slot p&3, issues DMA for half
// p+3 into slot (p+3)&3 (== slot(p-1), safely re-usable: its reads were
// lgkm-drained before the barrier entering phase p). Waits are inline-asm
// s_waitcnt vmcnt(6|5) lgkmcnt(0) + raw s_barrier -- NEVER vmcnt(0), so
// ~3 half-tile DMAs + 2 A-loads stay in flight across every barrier and
// the DMA port never drains (R1's exposed-transfer bottleneck).
// ---------------------------------------------------------------------------
__global__ __launch_bounds__(THR, 4)
void cluster_kernel(const float* __restrict__ x,
                    const _Float16* __restrict__ wsBall,
                    const float* __restrict__ csq,
                    float* __restrict__ out,
                    int ncopy) {
    extern __shared__ char smem[];
    char*  const ring   = smem;
    char*  const sA0    = smem + RING_BYTES;
    char*  const sA1    = sA0 + SA_BYTES;
    float* const xsq    = (float*)(smem + RING_BYTES + 2 * SA_BYTES);        // 64 f32
    float* const rowsum = (float*)(smem + RING_BYTES + 2 * SA_BYTES + 256);  // 64 f32

    const int t      = threadIdx.x;
    const int l      = t & 63;
    const int w      = t >> 6;          // 0..15
    const int lane16 = l & 15;
    const int kgrp   = l >> 4;          // 0..3
    const int row0   = blockIdx.x * RPB;

    const _Float16* const wb =
        wsBall + (size_t)(blockIdx.x % ncopy) * WSB_HALVES;

    if (t < 64) { xsq[t] = 0.f; rowsum[t] = 0.f; }
    __syncthreads();

    // fragment LDS byte offsets (invariant; slot base added per phase)
    const int abase = lane16 * SA_ROW_B + kgrp * 16;          // + rt*16*SA_ROW_B
    const int cloc0 = (w << 5) + lane16;
    const int cloc1 = cloc0 + 16;
    const int boff0 = cloc0 * 64 + ((kgrp + (cloc0 >> 1)) & 3) * 16;
    const int boff1 = cloc1 * 64 + ((kgrp + (cloc1 >> 1)) & 3) * 16;

    // A staging geometry: thread t loads one float2 per K-step
    const int ar = t >> 4;              // row 0..63
    const int ac = (t & 15) << 1;       // col 0,2,..,30 within the 32-k block
    const float* const aptr = x + (size_t)(row0 + ar) * DDIM + ac;
    const int awoff = ar * SA_ROW_B + ac * 2;   // LDS byte offset in A buf

#define DMAH(hp_) {                                                            \
        const _Float16* s_ = wb + (size_t)(hp_) * HT_HALVES;                   \
        char* d_ = ring + ((hp_) & 3) * HT_BYTES;                              \
        gload_lds16(s_ + t * 8, d_ + t * 16);                                  \
        gload_lds16(s_ + (1024 + t) * 8, d_ + (1024 + t) * 16);                \
    }

#define STAGE_A(f_, buf_) {                                                    \
        half2v h_; h_[0] = (_Float16)(f_)[0]; h_[1] = (_Float16)(f_)[1];       \
        *(half2v*)((buf_) + awoff) = h_;                                       \
        float ss_ = (f_)[0]*(f_)[0] + (f_)[1]*(f_)[1];                         \
        ss_ += __shfl_xor(ss_, 1, 64);                                         \
        ss_ += __shfl_xor(ss_, 2, 64);                                         \
        ss_ += __shfl_xor(ss_, 4, 64);                                         \
        ss_ += __shfl_xor(ss_, 8, 64);                                         \
        if ((t & 15) == 0) atomicAdd(&xsq[ar], ss_);                           \
    }

    floatx4 acc[4][4];
#pragma unroll
    for (int rt = 0; rt < 4; ++rt)
#pragma unroll
        for (int ct = 0; ct < 4; ++ct)
            acc[rt][ct] = (floatx4){0.f, 0.f, 0.f, 0.f};

    // ---- prologue: A(0),A(1) loads; DMA halves 0,1,2; stage A(0)
    floatx2 fA = __builtin_nontemporal_load((const floatx2*)aptr);          // A(0)
    DMAH(0); DMAH(1);
    floatx2 fB = __builtin_nontemporal_load((const floatx2*)(aptr + BK));   // A(1)
    DMAH(2);
    STAGE_A(fA, sA0);                       // consumes A(0) (implicit partial wait)
    asm volatile("s_waitcnt vmcnt(5) lgkmcnt(0)" ::: "memory");  // half 0 resident
    __builtin_amdgcn_s_barrier();

    // ---- 32-phase K loop
    half8 aF[4];
#pragma unroll
    for (int k = 0; k < KSTEPS; ++k) {
        char* const sAb = (k & 1) ? sA1 : sA0;
        char* const sAn = (k & 1) ? sA0 : sA1;   // buffer for step k+1
        // ---------- phase 2k (half 0): cols [0,512)
        {
            const char* slot = ring + ((2 * k) & 3) * HT_BYTES;
#pragma unroll
            for (int rt = 0; rt < 4; ++rt)
                aF[rt] = *(const half8*)(sAb + abase + rt * (16 * SA_ROW_B));
            const half8 b0 = *(const half8*)(slot + boff0);
            const half8 b1 = *(const half8*)(slot + boff1);
            if (2 * k + 3 <= NHALF - 1) DMAH(2 * k + 3);
            if (k + 2 <= KSTEPS - 1) {
                if ((k & 1) == 0)
                    fA = __builtin_nontemporal_load((const floatx2*)(aptr + (k + 2) * BK));
                else
                    fB = __builtin_nontemporal_load((const floatx2*)(aptr + (k + 2) * BK));
            }
            asm volatile("s_waitcnt vmcnt(6) lgkmcnt(0)" ::: "memory");  // half 2k+1 resident
            __builtin_amdgcn_s_barrier();
            __builtin_amdgcn_s_setprio(1);
#pragma unroll
            for (int rt = 0; rt < 4; ++rt) {
                acc[rt][0] = __builtin_amdgcn_mfma_f32_16x16x32_f16(aF[rt], b0, acc[rt][0], 0, 0, 0);
                acc[rt][1] = __builtin_amdgcn_mfma_f32_16x16x32_f16(aF[rt], b1, acc[rt][1], 0, 0, 0);
            }
            __builtin_amdgcn_s_setprio(0);
        }
        // ---------- phase 2k+1 (half 1): cols [512,1024)
        {
            const char* slot = ring + ((2 * k + 1) & 3) * HT_BYTES;
            const half8 b2 = *(const half8*)(slot + boff0);
            const half8 b3 = *(const half8*)(slot + boff1);
            if (2 * k + 4 <= NHALF - 1) DMAH(2 * k + 4);
            if (k + 1 <= KSTEPS - 1) {
                if ((k & 1) == 0) { STAGE_A(fB, sAn); }   // A(k+1), k even -> fB
                else              { STAGE_A(fA, sAn); }
            }
            asm volatile("s_waitcnt vmcnt(5) lgkmcnt(0)" ::: "memory");  // half 2k+2 resident
            __builtin_amdgcn_s_barrier();
            __builtin_amdgcn_s_setprio(1);
#pragma unroll
            for (int rt = 0; rt < 4; ++rt) {
                acc[rt][2] = __builtin_amdgcn_mfma_f32_16x16x32_f16(aF[rt], b2, acc[rt][2], 0, 0, 0);
                acc[rt][3] = __builtin_amdgcn_mfma_f32_16x16x32_f16(aF[rt], b3, acc[rt][3], 0, 0, 0);
            }
            __builtin_amdgcn_s_setprio(0);
        }
    }
#undef DMAH
#undef STAGE_A
    __syncthreads();

    // ---- epilogue. C layout: col = lane&15, row = (lane>>4)*4 + reg (m89/m91)
    // global col for ct: (ct>>1)*512 + w*32 + (ct&1)*16 + lane16
    float cs[4];
#pragma unroll
    for (int ct = 0; ct < 4; ++ct)
        cs[ct] = csq[(ct >> 1) * 512 + (w << 5) + (ct & 1) * 16 + lane16];
    floatx4 xv[4];
#pragma unroll
    for (int rt = 0; rt < 4; ++rt)
        xv[rt] = *(const floatx4*)(xsq + rt * 16 + kgrp * 4);

    float rp[4][4];
#pragma unroll
    for (int rt = 0; rt < 4; ++rt) {
#pragma unroll
        for (int i = 0; i < 4; ++i) {
            const float xr = xv[rt][i];
            float s = 0.f;
#pragma unroll
            for (int ct = 0; ct < 4; ++ct) {
                float d = xr + cs[ct] - 2.0f * acc[rt][ct][i];
                d = fmaxf(d, 0.0f);
                const float q = __builtin_amdgcn_rcpf(1.0f + d);   // ALPHA=1 -> exponent 1
                acc[rt][ct][i] = q;
                s += q;
            }
            rp[rt][i] = s;
        }
    }
    // reduce partial row sums across the 16 lanes sharing kgrp
#pragma unroll
    for (int m = 1; m <= 8; m <<= 1)
#pragma unroll
        for (int rt = 0; rt < 4; ++rt)
#pragma unroll
            for (int i = 0; i < 4; ++i)
                rp[rt][i] += __shfl_xor(rp[rt][i], m, 64);
    if (lane16 == 0) {
#pragma unroll
        for (int rt = 0; rt < 4; ++rt)
#pragma unroll
            for (int i = 0; i < 4; ++i)
                atomicAdd(&rowsum[rt * 16 + kgrp * 4 + i], rp[rt][i]);
    }
    __syncthreads();

    // plain (cached) stores: L2 merges the 64B lane-group quadrants into lines
#pragma unroll
    for (int rt = 0; rt < 4; ++rt) {
        const floatx4 rs = *(const floatx4*)(rowsum + rt * 16 + kgrp * 4);
#pragma unroll
        for (int i = 0; i < 4; ++i) {
            const float inv = __builtin_amdgcn_rcpf(rs[i]);
            float* orow = out + (size_t)(row0 + rt * 16 + kgrp * 4 + i) * KCL
                        + (w << 5) + lane16;
            orow[0]            = acc[rt][0][i] * inv;   // half0, ctl0
            orow[16]           = acc[rt][1][i] * inv;   // half0, ctl1
            orow[512]          = acc[rt][2][i] * inv;   // half1, ctl0
            orow[512 + 16]     = acc[rt][3][i] * inv;   // half1, ctl1
        }
    }
}

extern "C" void kernel_launch(void* const* d_in, const int* in_sizes, int n_in,
                              void* d_out, int out_size, void* d_ws, size_t ws_size,
                              hipStream_t stream) {
    (void)in_sizes; (void)n_in; (void)out_size;
    const float* x        = (const float*)d_in[0];
    const float* clusters = (const float*)d_in[1];
    float* out = (float*)d_out;

    // workspace: ncopy replicas of packed fp16 B (1 MiB each) + csq (4 KiB)
    int ncopy = (int)((ws_size - 4096) / (WSB_HALVES * 2));
    if (ncopy < 1) ncopy = 1;
    if (ncopy > 8) ncopy = 8;

    _Float16* wsB = (_Float16*)d_ws;
    float*    csq = (float*)((char*)d_ws + (size_t)ncopy * WSB_HALVES * 2);

    hipFuncSetAttribute((const void*)cluster_kernel,
                        hipFuncAttributeMaxDynamicSharedMemorySize, SMEM_BYTES);

    prep_kernel<<<256 * ncopy, 256, 0, stream>>>(clusters, wsB, csq);
    cluster_kernel<<<NBLK, THR, SMEM_BYTES, stream>>>(x, wsB, csq, out, ncopy);
}